// Round 5
// baseline (44944.839 us; speedup 1.0000x reference)
//
#include <hip/hip_runtime.h>
#include <math.h>

// Problem constants
#define BB   256    // batch
#define TT   1024   // timesteps
#define HH   512    // hidden
#define NWG  256    // 1 WG per CU
#define NTHR 512    // 8 waves
#define SLOT ((size_t)BB*HH)   // elements per h slot

typedef _Float16 f16;
typedef _Float16 f16x8 __attribute__((ext_vector_type(8)));
typedef float    f32x4 __attribute__((ext_vector_type(4)));
typedef unsigned long long u64;

__device__ __forceinline__ f32x4 mf(f16x8 a, f16x8 b, f32x4 c){
  return __builtin_amdgcn_mfma_f32_16x16x32_f16(a, b, c, 0, 0, 0);
}

__device__ __forceinline__ float fast_sigmoid(float v){
  float e = __expf(-v);
  return __builtin_amdgcn_rcpf(1.0f + e);
}
__device__ __forceinline__ float fast_tanh(float v){
  float a = fabsf(v);
  float e = __expf(-2.0f * a);
  float r = (1.0f - e) * __builtin_amdgcn_rcpf(1.0f + e);
  return copysignf(r, v);
}

// device-coherent write-through f16 store (lands at L3, the coherence point)
__device__ __forceinline__ void st_f16_wt(f16* p, f16 v){
  union { f16 f; unsigned short u; } cv; cv.f = v;
  __hip_atomic_store((unsigned short*)p, cv.u, __ATOMIC_RELAXED, __HIP_MEMORY_SCOPE_AGENT);
}
// device-coherent 16B fragment load as 2x8B relaxed atomics (bypass stale L1/L2;
// compiler still tracks vmcnt and software-pipelines these)
__device__ __forceinline__ f16x8 ld16_coh(const f16* p){
  union { u64 u[2]; f16x8 v; } r;
  r.u[0] = __hip_atomic_load((const u64*)p,     __ATOMIC_RELAXED, __HIP_MEMORY_SCOPE_AGENT);
  r.u[1] = __hip_atomic_load((const u64*)p + 1, __ATOMIC_RELAXED, __HIP_MEMORY_SCOPE_AGENT);
  return r.v;
}
__device__ __forceinline__ float ld_f16_coh(const f16* p){
  unsigned short u = __hip_atomic_load((const unsigned short*)p, __ATOMIC_RELAXED, __HIP_MEMORY_SCOPE_AGENT);
  union { unsigned short u; f16 f; } c; c.u = u;
  return (float)c.f;
}

// bar layout (unsigned words): [g*16] 32 group counters, [512] master, [544+r*16] 32 flag replicas.
// Arrival happens after __syncthreads, whose vmcnt(0) drain guarantees this WG's
// write-through stores have reached L3. Consumers read h with coherent loads, so
// NO cache fences are needed in the steady-state barrier.
__device__ __forceinline__ void gridbar_core(unsigned* bar, unsigned ph){
  const unsigned g = blockIdx.x & 31u;
  unsigned old = __hip_atomic_fetch_add(&bar[g*16], 1u, __ATOMIC_RELAXED, __HIP_MEMORY_SCOPE_AGENT);
  if (old + 1u == 8u*ph){                        // last of the 8 WGs in this group
    unsigned om = __hip_atomic_fetch_add(&bar[512], 1u, __ATOMIC_RELAXED, __HIP_MEMORY_SCOPE_AGENT);
    if (om + 1u == 32u*ph){                      // last group -> publish to all replicas
      #pragma unroll
      for (int r = 0; r < 32; ++r)
        __hip_atomic_store(&bar[544 + r*16], ph, __ATOMIC_RELAXED, __HIP_MEMORY_SCOPE_AGENT);
    }
  }
  while (__hip_atomic_load(&bar[544 + g*16], __ATOMIC_RELAXED, __HIP_MEMORY_SCOPE_AGENT) < ph){
    __builtin_amdgcn_s_sleep(2);
  }
}
// fence-free steady-state barrier
__device__ __forceinline__ void gridbar_nf(unsigned* bar, unsigned ph){
  __syncthreads();
  if (threadIdx.x == 0) gridbar_core(bar, ph);
  __syncthreads();
}
// fenced barrier (init only: makes plain-stored xT visible device-wide)
__device__ __forceinline__ void gridbar_f(unsigned* bar, unsigned ph){
  __syncthreads();
  if (threadIdx.x == 0){
    __builtin_amdgcn_fence(__ATOMIC_RELEASE, "agent");
    gridbar_core(bar, ph);
    __builtin_amdgcn_fence(__ATOMIC_ACQUIRE, "agent");
  }
  __syncthreads();
}

// ws layout (bytes): [0,8K) barrier, [8K, 8K+1M) xT fp32 [T][B],
// then 4 f16 planes of 2 slots each: h1hi, h1lo, h2hi, h2lo ([slot][b][k], k contig).
__global__ __launch_bounds__(NTHR, 2) void lstm_mfma(
    const float* __restrict__ x,      const float* __restrict__ W_ih1,
    const float* __restrict__ W_hh1,  const float* __restrict__ b1,
    const float* __restrict__ W_ih2,  const float* __restrict__ W_hh2,
    const float* __restrict__ b2,     const float* __restrict__ W_lin,
    const float* __restrict__ b_lin,  float* __restrict__ out,
    char* __restrict__ wsb)
{
  // A fragments in exact MFMA layout: index [chunk*64 + lane], 16B each.
  __shared__ f16x8 A2hi[2048], A2lo[2048], A1hi[1024], A1lo[1024]; // 96 KB
  __shared__ float xch[8][256];      // per-wave gate-exchange scratch
  __shared__ float wlin_s[512];
  __shared__ float outpart[2][8];

  unsigned* bar = (unsigned*)wsb;
  float* xT  = (float*)(wsb + 8192);
  f16* h1hi = (f16*)(wsb + 8192 + 1048576);
  f16* h1lo = h1hi + 2*SLOT;
  f16* h2hi = h1lo + 2*SLOT;
  f16* h2lo = h2hi + 2*SLOT;

  const int w   = blockIdx.x,  tid = threadIdx.x;
  const int l   = tid & 63,    wv  = tid >> 6;       // lane, wave
  const int quad = l >> 4,     lc  = l & 15;
  const int p = w >> 1, cb = w & 1;                  // row-group, batch half
  const int j0 = 4*p;                                // this WG's 4 hidden columns
  const int bcol = cb*128 + wv*16 + lc;              // this lane's batch column
  const int jq = j0 + quad;                          // this lane's j (post-exchange)

  // ---------------- init: weight split into LDS frag-order ----------------
  {
    const int g_ = lc >> 2, jj_ = lc & 3;            // A-row m = lc -> (gate, jj)
    const int wrow = g_*HH + j0 + jj_;
    const float* rowI  = W_ih2 + (size_t)wrow*HH;
    const float* rowH2 = W_hh2 + (size_t)wrow*HH;
    const float* rowH1 = W_hh1 + (size_t)wrow*HH;
    for (int c = wv; c < 32; c += 8){
      const int kb = c*32 + quad*8;
      union {f16x8 v; f16 e[8];} hi8, lo8;
      #pragma unroll
      for (int i = 0; i < 8; ++i){
        const int k = kb + i;
        const float wval = (k < HH) ? rowI[k] : rowH2[k - HH];
        const f16 h_ = (f16)wval;
        hi8.e[i] = h_;
        lo8.e[i] = (f16)((wval - (float)h_) * 2048.0f);
      }
      A2hi[c*64 + l] = hi8.v;
      A2lo[c*64 + l] = lo8.v;
    }
    for (int c = wv; c < 16; c += 8){
      const int kb = c*32 + quad*8;
      union {f16x8 v; f16 e[8];} hi8, lo8;
      #pragma unroll
      for (int i = 0; i < 8; ++i){
        const float wval = rowH1[kb + i];
        const f16 h_ = (f16)wval;
        hi8.e[i] = h_;
        lo8.e[i] = (f16)((wval - (float)h_) * 2048.0f);
      }
      A1hi[c*64 + l] = hi8.v;
      A1lo[c*64 + l] = lo8.v;
    }
  }
  // per-lane scalars (j = jq)
  float wih1r[4], b1r[4], b2r[4];
  #pragma unroll
  for (int g = 0; g < 4; ++g){
    wih1r[g] = W_ih1[g*HH + jq];
    b1r[g]   = b1[g*HH + jq];
    b2r[g]   = b2[g*HH + jq];
  }
  const float blin = b_lin[0];
  wlin_s[tid] = W_lin[tid];

  // x transpose -> xT[t][b] (plain stores; made visible by the fenced init barrier)
  {
    const int gid = w*NTHR + tid;
    #pragma unroll
    for (int i2 = 0; i2 < 2; ++i2){
      const int idx = gid + i2*131072;
      const int bb2 = idx >> 10, tt2 = idx & (TT-1);
      xT[(size_t)tt2*BB + bb2] = x[idx];
    }
  }
  // zero h2 slot 1 (read as h2(-1) at t=0) — write-through
  st_f16_wt(&h2hi[SLOT + (size_t)w*512 + tid], (f16)0.0f);
  st_f16_wt(&h2lo[SLOT + (size_t)w*512 + tid], (f16)0.0f);

  gridbar_f(bar, 1);

  // ---------------- prologue: h1(0), c-state init ----------------
  float c1, c2 = 0.0f;
  {
    const float xv0 = xT[bcol];
    const float gi = fast_sigmoid(fmaf(xv0, wih1r[0], b1r[0]));
    const float gg = fast_tanh   (fmaf(xv0, wih1r[2], b1r[2]));
    const float go = fast_sigmoid(fmaf(xv0, wih1r[3], b1r[3]));
    c1 = gi * gg;
    const float hv = go * fast_tanh(c1);
    const size_t ho = (size_t)bcol*HH + jq;          // slot 0
    const f16 hh = (f16)hv;
    st_f16_wt(&h1hi[ho], hh);
    st_f16_wt(&h1lo[ho], (f16)((hv - (float)hh)*2048.0f));
  }
  gridbar_f(bar, 2);

  // ---------------- main loop: phase t computes h2(t), h1(t+1), out(t-1) ----------------
  for (int t = 0; t < TT; ++t){
    const size_t sR1 = (size_t)( t    & 1)*SLOT;     // h1(t)      (read)
    const size_t sR2 = (size_t)((t+1) & 1)*SLOT;     // h2(t-1)    (read)
    const size_t sW1 = (size_t)((t+1) & 1)*SLOT;     // h1(t+1)    (write)
    const size_t sW2 = (size_t)( t    & 1)*SLOT;     // h2(t)      (write)

    const f16* p1h = h1hi + sR1 + (size_t)bcol*HH + quad*8;
    const f16* p1l = h1lo + sR1 + (size_t)bcol*HH + quad*8;
    const f16* p2h = h2hi + sR2 + (size_t)bcol*HH + quad*8;
    const f16* p2l = h2lo + sR2 + (size_t)bcol*HH + quad*8;

    // ---- burst-load h1 chunks (coherent 8B atomic loads, pipelined) ----
    f16x8 b1hv[16], b1lv[16];
    #pragma unroll
    for (int c = 0; c < 16; ++c){
      b1hv[c] = ld16_coh(p1h + c*32);
      b1lv[c] = ld16_coh(p1l + c*32);
    }

    // out(t-1) partial: thread tid covers k = tid
    float opart;
    {
      const size_t oi = sR2 + (size_t)w*HH + tid;
      const float hv = ld_f16_coh(&h2hi[oi]) + ld_f16_coh(&h2lo[oi])*(1.0f/2048.0f);
      opart = hv * wlin_s[tid];
    }

    f32x4 aA2 = {0,0,0,0}, aB2 = {0,0,0,0}, aA1 = {0,0,0,0}, aB1 = {0,0,0,0};

    // ---- h1 MFMA loop; interleave h2 loads (pipeline) ----
    f16x8 b2hv[16], b2lv[16];
    #pragma unroll
    for (int c = 0; c < 16; ++c){
      b2hv[c] = ld16_coh(p2h + c*32);
      b2lv[c] = ld16_coh(p2l + c*32);
      const f16x8 a2h = A2hi[c*64 + l];
      const f16x8 a2l = A2lo[c*64 + l];
      const f16x8 a1h = A1hi[c*64 + l];
      const f16x8 a1l = A1lo[c*64 + l];
      aA2 = mf(a2h, b1hv[c], aA2);
      aB2 = mf(a2h, b1lv[c], aB2);
      aB2 = mf(a2l, b1hv[c], aB2);
      aA1 = mf(a1h, b1hv[c], aA1);
      aB1 = mf(a1h, b1lv[c], aB1);
      aB1 = mf(a1l, b1hv[c], aB1);
    }
    // ---- h2 MFMA loop ----
    #pragma unroll
    for (int c = 0; c < 16; ++c){
      const f16x8 a2h = A2hi[(c+16)*64 + l];
      const f16x8 a2l = A2lo[(c+16)*64 + l];
      aA2 = mf(a2h, b2hv[c], aA2);
      aB2 = mf(a2h, b2lv[c], aB2);
      aB2 = mf(a2l, b2hv[c], aB2);
    }

    float* xw = &xch[wv][0];
    // ---- layer-2 cell (lane -> jj=quad, b=bcol after exchange) ----
    {
      f32x4 pre;
      #pragma unroll
      for (int i = 0; i < 4; ++i) pre[i] = fmaf(aB2[i], 1.0f/2048.0f, aA2[i]);
      *(f32x4*)&xw[lc*16 + quad*4] = pre;            // [col][row] layout
      __threadfence_block();
      const float g0 = xw[lc*16 + 0*4 + quad];
      const float g1 = xw[lc*16 + 1*4 + quad];
      const float g2 = xw[lc*16 + 2*4 + quad];
      const float g3 = xw[lc*16 + 3*4 + quad];
      const float gi = fast_sigmoid(g0 + b2r[0]);
      const float gf = fast_sigmoid(g1 + b2r[1]);
      const float gg = fast_tanh   (g2 + b2r[2]);
      const float go = fast_sigmoid(g3 + b2r[3]);
      c2 = fmaf(gf, c2, gi*gg);
      const float hv = go * fast_tanh(c2);
      const size_t ho = sW2 + (size_t)bcol*HH + jq;
      const f16 hh = (f16)hv;
      st_f16_wt(&h2hi[ho], hh);
      st_f16_wt(&h2lo[ho], (f16)((hv - (float)hh)*2048.0f));
    }
    // ---- layer-1 cell (for t+1) ----
    {
      f32x4 pre;
      #pragma unroll
      for (int i = 0; i < 4; ++i) pre[i] = fmaf(aB1[i], 1.0f/2048.0f, aA1[i]);
      __threadfence_block();                          // prior reads done before overwrite
      *(f32x4*)&xw[lc*16 + quad*4] = pre;
      __threadfence_block();
      const float g0 = xw[lc*16 + 0*4 + quad];
      const float g1 = xw[lc*16 + 1*4 + quad];
      const float g2 = xw[lc*16 + 2*4 + quad];
      const float g3 = xw[lc*16 + 3*4 + quad];
      const int tx = (t+1 < TT) ? (t+1) : (TT-1);
      const float xv = xT[(size_t)tx*BB + bcol];
      const float gi = fast_sigmoid(g0 + fmaf(xv, wih1r[0], b1r[0]));
      const float gf = fast_sigmoid(g1 + fmaf(xv, wih1r[1], b1r[1]));
      const float gg = fast_tanh   (g2 + fmaf(xv, wih1r[2], b1r[2]));
      const float go = fast_sigmoid(g3 + fmaf(xv, wih1r[3], b1r[3]));
      c1 = fmaf(gf, c1, gi*gg);
      const float hv = go * fast_tanh(c1);
      const size_t ho = sW1 + (size_t)bcol*HH + jq;
      const f16 hh = (f16)hv;
      st_f16_wt(&h1hi[ho], hh);
      st_f16_wt(&h1lo[ho], (f16)((hv - (float)hh)*2048.0f));
    }
    // ---- out(t-1) reduce ----
    #pragma unroll
    for (int off = 32; off > 0; off >>= 1) opart += __shfl_down(opart, off, 64);
    if (l == 0) outpart[t & 1][wv] = opart;

    gridbar_nf(bar, 3 + (unsigned)t);

    if (tid == 0 && t > 0){
      float s = blin;
      #pragma unroll
      for (int q2 = 0; q2 < 8; ++q2) s += outpart[t & 1][q2];
      out[(size_t)w*TT + (t-1)] = s;                 // plain store; flushed at kernel end
    }
  }

  // ---------------- tail: out(1023) ----------------
  {
    const size_t oi = (size_t)((TT-1)&1)*SLOT + (size_t)w*HH + tid;
    const float hv = ld_f16_coh(&h2hi[oi]) + ld_f16_coh(&h2lo[oi])*(1.0f/2048.0f);
    float opart = hv * wlin_s[tid];
    #pragma unroll
    for (int off = 32; off > 0; off >>= 1) opart += __shfl_down(opart, off, 64);
    if (l == 0) outpart[0][wv] = opart;
    __syncthreads();
    if (tid == 0){
      float s = blin;
      #pragma unroll
      for (int q2 = 0; q2 < 8; ++q2) s += outpart[0][q2];
      out[(size_t)w*TT + (TT-1)] = s;
    }
  }
}

extern "C" void kernel_launch(void* const* d_in, const int* in_sizes, int n_in,
                              void* d_out, int out_size, void* d_ws, size_t ws_size,
                              hipStream_t stream) {
  const float* x     = (const float*)d_in[0];
  const float* W_ih1 = (const float*)d_in[1];
  const float* W_hh1 = (const float*)d_in[2];
  const float* b1    = (const float*)d_in[3];
  const float* W_ih2 = (const float*)d_in[4];
  const float* W_hh2 = (const float*)d_in[5];
  const float* b2    = (const float*)d_in[6];
  const float* W_lin = (const float*)d_in[7];
  const float* b_lin = (const float*)d_in[8];
  float* out = (float*)d_out;
  char* wsb  = (char*)d_ws;

  // zero the barrier region (ws is re-poisoned to 0xAA before every launch)
  hipMemsetAsync(d_ws, 0, 8192, stream);

  hipLaunchKernelGGL(lstm_mfma, dim3(NWG), dim3(NTHR), 0, stream,
                     x, W_ih1, W_hh1, b1, W_ih2, W_hh2, b2, W_lin, b_lin, out, wsb);
}

// Round 6
// 14441.661 us; speedup vs baseline: 3.1122x; 3.1122x over previous
//
#include <hip/hip_runtime.h>
#include <math.h>

// Problem constants
#define BB   256    // batch
#define TT   1024   // timesteps
#define HH   512    // hidden
#define NWG  256    // 1 WG per CU
#define NTHR 512    // 8 waves
#define SLOT (HH*BB)   // u32 elements per h slot (packed hi|lo)

typedef _Float16 f16;
typedef _Float16 f16x8 __attribute__((ext_vector_type(8)));
typedef float    f32x4 __attribute__((ext_vector_type(4)));
typedef unsigned int u32;

__device__ __forceinline__ f32x4 mf(f16x8 a, f16x8 b, f32x4 c){
  return __builtin_amdgcn_mfma_f32_16x16x32_f16(a, b, c, 0, 0, 0);
}

__device__ __forceinline__ float fast_sigmoid(float v){
  float e = __expf(-v);
  return __builtin_amdgcn_rcpf(1.0f + e);
}
__device__ __forceinline__ float fast_tanh(float v){
  float a = fabsf(v);
  float e = __expf(-2.0f * a);
  float r = (1.0f - e) * __builtin_amdgcn_rcpf(1.0f + e);
  return copysignf(r, v);
}

// pack fp32 -> (hi f16 | lo f16<<16), lo pre-scaled by 2^11
__device__ __forceinline__ u32 pack_hl(float hv){
  const f16 hh = (f16)hv;
  const f16 ll = (f16)((hv - (float)hh) * 2048.0f);
  union {f16 f; unsigned short u;} ch, cl; ch.f = hh; cl.f = ll;
  return (u32)ch.u | ((u32)cl.u << 16);
}
__device__ __forceinline__ float unpack_f(u32 v){
  union {unsigned short u; f16 f;} h, l;
  h.u = (unsigned short)(v & 0xffffu);
  l.u = (unsigned short)(v >> 16);
  return (float)h.f + (float)l.f * (1.0f/2048.0f);
}
// device-coherent write-through u32 store (dense: one full 64B line per quad)
__device__ __forceinline__ void st_u32_wt(u32* p, u32 v){
  __hip_atomic_store(p, v, __ATOMIC_RELAXED, __HIP_MEMORY_SCOPE_AGENT);
}

// build hi/lo f16x8 fragments from 8 packed u32 at stride BB (k-major layout)
__device__ __forceinline__ void build_frag(const u32* pk, f16x8& fh, f16x8& fl){
  u32 v[8];
  #pragma unroll
  for (int i = 0; i < 8; ++i) v[i] = pk[i*BB];
  union {u32 u[4]; f16x8 f;} H, L;
  #pragma unroll
  for (int j = 0; j < 4; ++j){
    H.u[j] = __builtin_amdgcn_perm(v[2*j+1], v[2*j], 0x05040100u); // lo16 pair
    L.u[j] = __builtin_amdgcn_perm(v[2*j+1], v[2*j], 0x07060302u); // hi16 pair
  }
  fh = H.f; fl = L.f;
}

// hierarchical fenced grid barrier, distributed flags (R4-proven).
// bar words: [g*16] 32 group counters, [512] master, [544+r*16] 32 flag replicas.
__device__ __forceinline__ void gridbar(unsigned* bar, unsigned ph){
  __syncthreads();
  if (threadIdx.x == 0){
    __builtin_amdgcn_fence(__ATOMIC_RELEASE, "agent");
    const unsigned g = blockIdx.x & 31u;
    unsigned old = __hip_atomic_fetch_add(&bar[g*16], 1u, __ATOMIC_RELAXED, __HIP_MEMORY_SCOPE_AGENT);
    if (old + 1u == 8u*ph){
      unsigned om = __hip_atomic_fetch_add(&bar[512], 1u, __ATOMIC_RELAXED, __HIP_MEMORY_SCOPE_AGENT);
      if (om + 1u == 32u*ph){
        #pragma unroll
        for (int r = 0; r < 32; ++r)
          __hip_atomic_store(&bar[544 + r*16], ph, __ATOMIC_RELAXED, __HIP_MEMORY_SCOPE_AGENT);
      }
    }
    while (__hip_atomic_load(&bar[544 + g*16], __ATOMIC_RELAXED, __HIP_MEMORY_SCOPE_AGENT) < ph){
      __builtin_amdgcn_s_sleep(2);
    }
    __builtin_amdgcn_fence(__ATOMIC_ACQUIRE, "agent");
  }
  __syncthreads();
}

// ws layout (bytes): [0,8K) barrier, [8K, 8K+1M) xT fp32 [T][B],
// then 2 packed-u32 planes of 2 slots each: h1p, h2p ([slot][k][b], b contig).
__global__ __launch_bounds__(NTHR, 2) void lstm_mfma(
    const float* __restrict__ x,      const float* __restrict__ W_ih1,
    const float* __restrict__ W_hh1,  const float* __restrict__ b1,
    const float* __restrict__ W_ih2,  const float* __restrict__ W_hh2,
    const float* __restrict__ b2,     const float* __restrict__ W_lin,
    const float* __restrict__ b_lin,  float* __restrict__ out,
    char* __restrict__ wsb)
{
  // A fragments in exact MFMA layout: index [chunk*64 + lane], 16B each.
  __shared__ f16x8 A2hi[2048], A2lo[2048], A1hi[1024], A1lo[1024]; // 96 KB
  __shared__ float xch[8][256];      // per-wave gate-exchange scratch
  __shared__ float wlin_s[512];
  __shared__ float outpart[2][8];

  unsigned* bar = (unsigned*)wsb;
  float* xT = (float*)(wsb + 8192);
  u32* h1p = (u32*)(wsb + 8192 + 1048576);   // 2 slots
  u32* h2p = h1p + 2*SLOT;                    // 2 slots

  const int w   = blockIdx.x,  tid = threadIdx.x;
  const int l   = tid & 63,    wv  = tid >> 6;       // lane, wave
  const int quad = l >> 4,     lc  = l & 15;
  const int p = w >> 1, cb = w & 1;                  // row-group, batch half
  const int j0 = 4*p;                                // this WG's 4 hidden columns
  const int bcol = cb*128 + wv*16 + lc;              // this lane's batch column
  const int jq = j0 + quad;                          // this lane's j (post-exchange)

  // ---------------- init: weight split into LDS frag-order ----------------
  {
    const int g_ = lc >> 2, jj_ = lc & 3;            // A-row m = lc -> (gate, jj)
    const int wrow = g_*HH + j0 + jj_;
    const float* rowI  = W_ih2 + (size_t)wrow*HH;
    const float* rowH2 = W_hh2 + (size_t)wrow*HH;
    const float* rowH1 = W_hh1 + (size_t)wrow*HH;
    for (int c = wv; c < 32; c += 8){
      const int kb = c*32 + quad*8;
      union {f16x8 v; f16 e[8];} hi8, lo8;
      #pragma unroll
      for (int i = 0; i < 8; ++i){
        const int k = kb + i;
        const float wval = (k < HH) ? rowI[k] : rowH2[k - HH];
        const f16 h_ = (f16)wval;
        hi8.e[i] = h_;
        lo8.e[i] = (f16)((wval - (float)h_) * 2048.0f);
      }
      A2hi[c*64 + l] = hi8.v;
      A2lo[c*64 + l] = lo8.v;
    }
    for (int c = wv; c < 16; c += 8){
      const int kb = c*32 + quad*8;
      union {f16x8 v; f16 e[8];} hi8, lo8;
      #pragma unroll
      for (int i = 0; i < 8; ++i){
        const float wval = rowH1[kb + i];
        const f16 h_ = (f16)wval;
        hi8.e[i] = h_;
        lo8.e[i] = (f16)((wval - (float)h_) * 2048.0f);
      }
      A1hi[c*64 + l] = hi8.v;
      A1lo[c*64 + l] = lo8.v;
    }
  }
  // per-lane scalars (j = jq)
  float wih1r[4], b1r[4], b2r[4];
  #pragma unroll
  for (int g = 0; g < 4; ++g){
    wih1r[g] = W_ih1[g*HH + jq];
    b1r[g]   = b1[g*HH + jq];
    b2r[g]   = b2[g*HH + jq];
  }
  const float blin = b_lin[0];
  wlin_s[tid] = W_lin[tid];

  // x transpose -> xT[t][b] (plain stores; made visible by the fenced barrier)
  {
    const int gid = w*NTHR + tid;
    #pragma unroll
    for (int i2 = 0; i2 < 2; ++i2){
      const int idx = gid + i2*131072;
      const int bb2 = idx >> 10, tt2 = idx & (TT-1);
      xT[(size_t)tt2*BB + bb2] = x[idx];
    }
  }
  // zero h2 slot 1 (read as h2(-1) at t=0) — dense write-through
  st_u32_wt(&h2p[SLOT + w*NTHR + tid], 0u);

  gridbar(bar, 1);

  // ---------------- prologue: h1(0), c-state init ----------------
  float c1, c2 = 0.0f;
  {
    const float xv0 = xT[bcol];
    const float gi = fast_sigmoid(fmaf(xv0, wih1r[0], b1r[0]));
    const float gg = fast_tanh   (fmaf(xv0, wih1r[2], b1r[2]));
    const float go = fast_sigmoid(fmaf(xv0, wih1r[3], b1r[3]));
    c1 = gi * gg;
    const float hv = go * fast_tanh(c1);
    st_u32_wt(&h1p[jq*BB + bcol], pack_hl(hv));      // slot 0, [k][b]
  }
  gridbar(bar, 2);

  // ---------------- main loop: phase t computes h2(t), h1(t+1), out(t-1) ----------------
  for (int t = 0; t < TT; ++t){
    const int sR1 = ( t    & 1)*SLOT;     // h1(t)      (read)
    const int sR2 = ((t+1) & 1)*SLOT;     // h2(t-1)    (read)
    const int sW1 = ((t+1) & 1)*SLOT;     // h1(t+1)    (write)
    const int sW2 = ( t    & 1)*SLOT;     // h2(t)      (write)

    // out(t-1) partial: thread tid covers k = tid (plane is [k][b], b = w)
    float opart = unpack_f(h2p[sR2 + tid*BB + w]) * wlin_s[tid];

    f32x4 aA2 = {0,0,0,0}, aB2 = {0,0,0,0}, aA1 = {0,0,0,0}, aB1 = {0,0,0,0};
    const u32* q1 = h1p + sR1 + bcol + quad*8*BB;
    const u32* q2 = h2p + sR2 + bcol + quad*8*BB;

    // ---- h1(t) chunks: feed both the L2 tile and the L1 tile ----
    #pragma unroll
    for (int c = 0; c < 16; ++c){
      f16x8 bh, bl;
      build_frag(q1 + c*32*BB, bh, bl);
      const f16x8 a2h = A2hi[c*64 + l];
      const f16x8 a2l = A2lo[c*64 + l];
      const f16x8 a1h = A1hi[c*64 + l];
      const f16x8 a1l = A1lo[c*64 + l];
      aA2 = mf(a2h, bh, aA2);
      aB2 = mf(a2h, bl, aB2);
      aB2 = mf(a2l, bh, aB2);
      aA1 = mf(a1h, bh, aA1);
      aB1 = mf(a1h, bl, aB1);
      aB1 = mf(a1l, bh, aB1);
    }
    // ---- h2(t-1) chunks: L2 tile only ----
    #pragma unroll
    for (int c = 0; c < 16; ++c){
      f16x8 bh, bl;
      build_frag(q2 + c*32*BB, bh, bl);
      const f16x8 a2h = A2hi[(c+16)*64 + l];
      const f16x8 a2l = A2lo[(c+16)*64 + l];
      aA2 = mf(a2h, bh, aA2);
      aB2 = mf(a2h, bl, aB2);
      aB2 = mf(a2l, bh, aB2);
    }

    float* xw = &xch[wv][0];
    // ---- layer-2 cell (lane -> jj=quad, b=bcol after exchange) ----
    {
      f32x4 pre;
      #pragma unroll
      for (int i = 0; i < 4; ++i) pre[i] = fmaf(aB2[i], 1.0f/2048.0f, aA2[i]);
      *(f32x4*)&xw[lc*16 + quad*4] = pre;            // [col][row] layout
      __threadfence_block();
      const float g0 = xw[lc*16 + 0*4 + quad];
      const float g1 = xw[lc*16 + 1*4 + quad];
      const float g2 = xw[lc*16 + 2*4 + quad];
      const float g3 = xw[lc*16 + 3*4 + quad];
      const float gi = fast_sigmoid(g0 + b2r[0]);
      const float gf = fast_sigmoid(g1 + b2r[1]);
      const float gg = fast_tanh   (g2 + b2r[2]);
      const float go = fast_sigmoid(g3 + b2r[3]);
      c2 = fmaf(gf, c2, gi*gg);
      const float hv = go * fast_tanh(c2);
      st_u32_wt(&h2p[sW2 + jq*BB + bcol], pack_hl(hv));  // dense [k][b]
    }
    // ---- layer-1 cell (for t+1) ----
    {
      f32x4 pre;
      #pragma unroll
      for (int i = 0; i < 4; ++i) pre[i] = fmaf(aB1[i], 1.0f/2048.0f, aA1[i]);
      __threadfence_block();                          // prior reads done before overwrite
      *(f32x4*)&xw[lc*16 + quad*4] = pre;
      __threadfence_block();
      const float g0 = xw[lc*16 + 0*4 + quad];
      const float g1 = xw[lc*16 + 1*4 + quad];
      const float g2 = xw[lc*16 + 2*4 + quad];
      const float g3 = xw[lc*16 + 3*4 + quad];
      const int tx = (t+1 < TT) ? (t+1) : (TT-1);
      const float xv = xT[(size_t)tx*BB + bcol];
      const float gi = fast_sigmoid(g0 + fmaf(xv, wih1r[0], b1r[0]));
      const float gf = fast_sigmoid(g1 + fmaf(xv, wih1r[1], b1r[1]));
      const float gg = fast_tanh   (g2 + fmaf(xv, wih1r[2], b1r[2]));
      const float go = fast_sigmoid(g3 + fmaf(xv, wih1r[3], b1r[3]));
      c1 = fmaf(gf, c1, gi*gg);
      const float hv = go * fast_tanh(c1);
      st_u32_wt(&h1p[sW1 + jq*BB + bcol], pack_hl(hv));  // dense [k][b]
    }
    // ---- out(t-1) reduce ----
    #pragma unroll
    for (int off = 32; off > 0; off >>= 1) opart += __shfl_down(opart, off, 64);
    if (l == 0) outpart[t & 1][wv] = opart;

    gridbar(bar, 3 + (unsigned)t);

    if (tid == 0 && t > 0){
      float s = blin;
      #pragma unroll
      for (int q2i = 0; q2i < 8; ++q2i) s += outpart[t & 1][q2i];
      out[(size_t)w*TT + (t-1)] = s;                 // plain store; flushed at kernel end
    }
  }

  // ---------------- tail: out(1023) ----------------
  {
    float opart = unpack_f(h2p[((TT-1)&1)*SLOT + tid*BB + w]) * wlin_s[tid];
    #pragma unroll
    for (int off = 32; off > 0; off >>= 1) opart += __shfl_down(opart, off, 64);
    if (l == 0) outpart[0][wv] = opart;
    __syncthreads();
    if (tid == 0){
      float s = blin;
      #pragma unroll
      for (int q2i = 0; q2i < 8; ++q2i) s += outpart[0][q2i];
      out[(size_t)w*TT + (TT-1)] = s;
    }
  }
}

extern "C" void kernel_launch(void* const* d_in, const int* in_sizes, int n_in,
                              void* d_out, int out_size, void* d_ws, size_t ws_size,
                              hipStream_t stream) {
  const float* x     = (const float*)d_in[0];
  const float* W_ih1 = (const float*)d_in[1];
  const float* W_hh1 = (const float*)d_in[2];
  const float* b1    = (const float*)d_in[3];
  const float* W_ih2 = (const float*)d_in[4];
  const float* W_hh2 = (const float*)d_in[5];
  const float* b2    = (const float*)d_in[6];
  const float* W_lin = (const float*)d_in[7];
  const float* b_lin = (const float*)d_in[8];
  float* out = (float*)d_out;
  char* wsb  = (char*)d_ws;

  // zero the barrier region (ws is re-poisoned to 0xAA before every launch)
  hipMemsetAsync(d_ws, 0, 8192, stream);

  hipLaunchKernelGGL(lstm_mfma, dim3(NWG), dim3(NTHR), 0, stream,
                     x, W_ih1, W_hh1, b1, W_ih2, W_hh2, b2, W_lin, b_lin, out, wsb);
}